// Round 1
// baseline (719.772 us; speedup 1.0000x reference)
//
#include <hip/hip_runtime.h>
#include <math.h>

namespace {

constexpr int Bn = 65536;
constexpr int Dn = 1024;
constexpr int Cn = 256;
constexpr int Pn = 32;
constexpr int Hn = 128;
constexpr int In = 32;
constexpr int En = 16;
constexpr int Fn = 1056;          // D + P
constexpr int Rn = 64;            // rows per block
constexpr int KC = 32;            // K-chunk for gp1 GEMM (1056 = 33*32)
constexpr int NCH = Fn / KC;      // 33 chunks
constexpr int FS = KC + 4;        // fbuf stride (pad: bank spread + 16B align)
constexpr int HS = Hn + 4;        // hbuf stride

__device__ __forceinline__ float gelu_f(float v) {
    // exact (erf) GELU, matching jax.nn.gelu(approximate=False)
    return 0.5f * v * (1.0f + erff(v * 0.70710678118654752440f));
}

__global__ __launch_bounds__(256, 2)
void cag_fused(const float* __restrict__ x, const float* __restrict__ ctx,
               const float* __restrict__ en_g, const float* __restrict__ en_b,
               const float* __restrict__ cn_g, const float* __restrict__ cn_b,
               const float* __restrict__ cp1_w, const float* __restrict__ cp1_b,
               const float* __restrict__ cp2_w, const float* __restrict__ cp2_b,
               const float* __restrict__ cpn_g, const float* __restrict__ cpn_b,
               const float* __restrict__ fn_g, const float* __restrict__ fn_b,
               const float* __restrict__ gp1_w, const float* __restrict__ gp1_b,
               const float* __restrict__ ln1_g, const float* __restrict__ ln1_b,
               const float* __restrict__ gp2_w, const float* __restrict__ gp2_b,
               const float* __restrict__ ln2_g, const float* __restrict__ ln2_b,
               const float* __restrict__ gp3_w, const float* __restrict__ gp3_b,
               float* __restrict__ out)
{
    __shared__ union U {
        struct { float wbuf[KC][Hn]; float fbuf[Rn][FS]; } p2;  // 16K + 9K
        struct { float hbuf[Rn][HS]; } p3;                      // 33K
        struct { float ctxn[4][Cn]; } p0;                       // 4K
    } sm;
    __shared__ float cfn[Rn][Pn];                               // 8K, persists
    __shared__ float s_xm[Rn], s_xr[Rn], s_fm[Rn], s_fr[Rn];
    __shared__ float s_cfs[Rn], s_cfs2[Rn];
    __shared__ float interL[Rn][In + 1];                        // 8.4K
    __shared__ float logitsL[Rn][En];                           // 4K

    const int tid  = threadIdx.x;
    const int lane = tid & 63;
    const int wv   = tid >> 6;
    const int row0 = blockIdx.x * Rn;

    // ---------------- Phase 0: context branch -> cfn[r][32] + its sums ----
    for (int rr = wv; rr < Rn; rr += 4) {
        const float4 cv = ((const float4*)(ctx + (size_t)(row0 + rr) * Cn))[lane];
        float s  = cv.x + cv.y + cv.z + cv.w;
        float s2 = cv.x*cv.x + cv.y*cv.y + cv.z*cv.z + cv.w*cv.w;
        #pragma unroll
        for (int m = 1; m <= 32; m <<= 1) { s += __shfl_xor(s, m, 64); s2 += __shfl_xor(s2, m, 64); }
        const float mean = s * (1.0f / Cn);
        const float rstd = rsqrtf(s2 * (1.0f / Cn) - mean * mean + 1e-5f);
        float* cb = sm.p0.ctxn[wv];
        const int c4 = lane * 4;
        cb[c4 + 0] = (cv.x - mean) * rstd * cn_g[c4 + 0] + cn_b[c4 + 0];
        cb[c4 + 1] = (cv.y - mean) * rstd * cn_g[c4 + 1] + cn_b[c4 + 1];
        cb[c4 + 2] = (cv.z - mean) * rstd * cn_g[c4 + 2] + cn_b[c4 + 2];
        cb[c4 + 3] = (cv.w - mean) * rstd * cn_g[c4 + 3] + cn_b[c4 + 3];
        __syncthreads();
        // cp1: lane = p + 32*half; each half sums 128 of the 256 c's
        const int p = lane & 31, half = lane >> 5;
        const int cbase = half * 128;
        float a1 = 0.f;
        #pragma unroll 4
        for (int c = 0; c < 128; ++c)
            a1 = fmaf(cb[cbase + c], cp1_w[(cbase + c) * Pn + p], a1);
        a1 += __shfl_xor(a1, 32, 64);
        a1 = gelu_f(a1 + cp1_b[p]);
        // cp2 via lane broadcasts
        float a2 = 0.f;
        #pragma unroll
        for (int q = 0; q < 32; ++q)
            a2 = fmaf(__shfl(a1, q, 64), cp2_w[q * Pn + p], a2);
        a2 += cp2_b[p];
        // LN over P=32 (within 32-lane half)
        float t = a2, t2 = a2 * a2;
        #pragma unroll
        for (int m = 1; m <= 16; m <<= 1) { t += __shfl_xor(t, m, 64); t2 += __shfl_xor(t2, m, 64); }
        const float pm  = t * (1.0f / Pn);
        const float prs = rsqrtf(t2 * (1.0f / Pn) - pm * pm + 1e-5f);
        const float cno = (a2 - pm) * prs * cpn_g[p] + cpn_b[p];
        float cs = cno, cs2 = cno * cno;
        #pragma unroll
        for (int m = 1; m <= 16; m <<= 1) { cs += __shfl_xor(cs, m, 64); cs2 += __shfl_xor(cs2, m, 64); }
        if (half == 0) {
            cfn[rr][p] = cno;
            if (p == 0) { s_cfs[rr] = cs; s_cfs2[rr] = cs2; }
        }
        __syncthreads();
    }

    // ---------------- Phase 1a: x row stats (HBM read of x) ----------------
    __syncthreads();
    for (int rr = wv; rr < Rn; rr += 4) {
        const float4* xr = (const float4*)(x + (size_t)(row0 + rr) * Dn);
        float s = 0.f, s2 = 0.f;
        #pragma unroll
        for (int q = 0; q < 4; ++q) {
            const float4 v = xr[lane + 64 * q];
            s  += v.x + v.y + v.z + v.w;
            s2 += v.x*v.x + v.y*v.y + v.z*v.z + v.w*v.w;
        }
        #pragma unroll
        for (int m = 1; m <= 32; m <<= 1) { s += __shfl_xor(s, m, 64); s2 += __shfl_xor(s2, m, 64); }
        if (lane == 0) {
            const float mean = s * (1.0f / Dn);
            s_xm[rr] = mean;
            s_xr[rr] = rsqrtf(s2 * (1.0f / Dn) - mean * mean + 1e-5f);
        }
    }
    __syncthreads();

    // ---------------- Phase 1b: fusion LN stats (x re-read from L2/L3) -----
    {
        float4 eg[4], eb[4];
        #pragma unroll
        for (int q = 0; q < 4; ++q) {
            eg[q] = ((const float4*)en_g)[lane + 64 * q];
            eb[q] = ((const float4*)en_b)[lane + 64 * q];
        }
        for (int rr = wv; rr < Rn; rr += 4) {
            const float4* xr = (const float4*)(x + (size_t)(row0 + rr) * Dn);
            const float xm = s_xm[rr], xrs = s_xr[rr];
            float s = 0.f, s2 = 0.f;
            #pragma unroll
            for (int q = 0; q < 4; ++q) {
                const float4 v = xr[lane + 64 * q];
                float e;
                e = (v.x - xm) * xrs * eg[q].x + eb[q].x; s += e; s2 += e*e;
                e = (v.y - xm) * xrs * eg[q].y + eb[q].y; s += e; s2 += e*e;
                e = (v.z - xm) * xrs * eg[q].z + eb[q].z; s += e; s2 += e*e;
                e = (v.w - xm) * xrs * eg[q].w + eb[q].w; s += e; s2 += e*e;
            }
            #pragma unroll
            for (int m = 1; m <= 32; m <<= 1) { s += __shfl_xor(s, m, 64); s2 += __shfl_xor(s2, m, 64); }
            if (lane == 0) {
                const float fmn = (s + s_cfs[rr]) * (1.0f / Fn);
                s_fm[rr] = fmn;
                s_fr[rr] = rsqrtf((s2 + s_cfs2[rr]) * (1.0f / Fn) - fmn * fmn + 1e-5f);
            }
        }
    }
    __syncthreads();

    // ---------------- Phase 2: gp1 GEMM [64 x 1056] @ [1056 x 128] ---------
    float acc[8][4];
    #pragma unroll
    for (int j = 0; j < 8; ++j) { acc[j][0]=0.f; acc[j][1]=0.f; acc[j][2]=0.f; acc[j][3]=0.f; }
    const int tc = tid & 31, tr = tid >> 5;
    const int c0 = tc * 4, r0 = tr * 8;
    const int kq = tid & 7, rloc = tid >> 3;
    const int kk0 = kq * 4;

    for (int ch = 0; ch < NCH; ++ch) {
        const int kc0 = ch * KC;
        __syncthreads();   // previous chunk's reads done before overwrite
        // stage W chunk [32 x 128]
        #pragma unroll
        for (int it = 0; it < 4; ++it) {
            const int idx = it * 1024 + tid * 4;
            const int kk = idx >> 7, h = idx & 127;
            const float4 wvv = *(const float4*)(gp1_w + (size_t)(kc0 + kk) * Hn + h);
            *(float4*)&sm.p2.wbuf[kk][h] = wvv;
        }
        // stage fusion chunk [64 x 32] (fused emb-LN + fusion-LN on the fly)
        if (ch < NCH - 1) {
            const float4 egv = *(const float4*)(en_g + kc0 + kk0);
            const float4 ebv = *(const float4*)(en_b + kc0 + kk0);
            const float4 fgv = *(const float4*)(fn_g + kc0 + kk0);
            const float4 fbv = *(const float4*)(fn_b + kc0 + kk0);
            #pragma unroll
            for (int rg = 0; rg < 2; ++rg) {
                const int r = rg * 32 + rloc;
                const float xm = s_xm[r], xrs = s_xr[r], fmn = s_fm[r], frs = s_fr[r];
                const float4 v = *(const float4*)(x + (size_t)(row0 + r) * Dn + kc0 + kk0);
                float4 fo; float e;
                e = (v.x - xm) * xrs * egv.x + ebv.x; fo.x = (e - fmn) * frs * fgv.x + fbv.x;
                e = (v.y - xm) * xrs * egv.y + ebv.y; fo.y = (e - fmn) * frs * fgv.y + fbv.y;
                e = (v.z - xm) * xrs * egv.z + ebv.z; fo.z = (e - fmn) * frs * fgv.z + fbv.z;
                e = (v.w - xm) * xrs * egv.w + ebv.w; fo.w = (e - fmn) * frs * fgv.w + fbv.w;
                *(float4*)&sm.p2.fbuf[r][kk0] = fo;
            }
        } else {  // last chunk: the cf part (k = 1024..1055)
            const float4 fgv = *(const float4*)(fn_g + kc0 + kk0);
            const float4 fbv = *(const float4*)(fn_b + kc0 + kk0);
            #pragma unroll
            for (int rg = 0; rg < 2; ++rg) {
                const int r = rg * 32 + rloc;
                const float fmn = s_fm[r], frs = s_fr[r];
                float4 fo;
                fo.x = (cfn[r][kk0 + 0] - fmn) * frs * fgv.x + fbv.x;
                fo.y = (cfn[r][kk0 + 1] - fmn) * frs * fgv.y + fbv.y;
                fo.z = (cfn[r][kk0 + 2] - fmn) * frs * fgv.z + fbv.z;
                fo.w = (cfn[r][kk0 + 3] - fmn) * frs * fgv.w + fbv.w;
                *(float4*)&sm.p2.fbuf[r][kk0] = fo;
            }
        }
        __syncthreads();
        // register-tiled FMA: 8 rows x 4 cols per thread
        #pragma unroll 4
        for (int kk = 0; kk < KC; ++kk) {
            const float4 bv = *(const float4*)&sm.p2.wbuf[kk][c0];
            float av[8];
            #pragma unroll
            for (int j = 0; j < 8; ++j) av[j] = sm.p2.fbuf[r0 + j][kk];
            #pragma unroll
            for (int j = 0; j < 8; ++j) {
                acc[j][0] = fmaf(av[j], bv.x, acc[j][0]);
                acc[j][1] = fmaf(av[j], bv.y, acc[j][1]);
                acc[j][2] = fmaf(av[j], bv.z, acc[j][2]);
                acc[j][3] = fmaf(av[j], bv.w, acc[j][3]);
            }
        }
    }

    // ---------------- Phase 3a: +bias, LN1 over H, gelu -> hbuf ------------
    __syncthreads();
    {
        const float4 b1  = *(const float4*)(gp1_b + c0);
        const float4 g1  = *(const float4*)(ln1_g + c0);
        const float4 bb1 = *(const float4*)(ln1_b + c0);
        #pragma unroll
        for (int j = 0; j < 8; ++j) {
            const float h0 = acc[j][0] + b1.x, h1 = acc[j][1] + b1.y;
            const float h2 = acc[j][2] + b1.z, h3 = acc[j][3] + b1.w;
            float s  = h0 + h1 + h2 + h3;
            float s2 = h0*h0 + h1*h1 + h2*h2 + h3*h3;
            #pragma unroll
            for (int m = 1; m <= 16; m <<= 1) { s += __shfl_xor(s, m, 64); s2 += __shfl_xor(s2, m, 64); }
            const float mean = s * (1.0f / Hn);
            const float rstd = rsqrtf(s2 * (1.0f / Hn) - mean * mean + 1e-5f);
            float4 hv;
            hv.x = gelu_f((h0 - mean) * rstd * g1.x + bb1.x);
            hv.y = gelu_f((h1 - mean) * rstd * g1.y + bb1.y);
            hv.z = gelu_f((h2 - mean) * rstd * g1.z + bb1.z);
            hv.w = gelu_f((h3 - mean) * rstd * g1.w + bb1.w);
            *(float4*)&sm.p3.hbuf[r0 + j][c0] = hv;
        }
    }
    __syncthreads();

    // ---------------- Phase 3b: gp2 (128->32), LN2, gelu -> interL ---------
    {
        const int i_ = tid & 31, rg2 = tid >> 5;
        float a2[8] = {0.f,0.f,0.f,0.f,0.f,0.f,0.f,0.f};
        #pragma unroll 4
        for (int k = 0; k < Hn; ++k) {
            const float w2v = gp2_w[k * In + i_];
            #pragma unroll
            for (int j = 0; j < 8; ++j)
                a2[j] = fmaf(sm.p3.hbuf[rg2 * 8 + j][k], w2v, a2[j]);
        }
        const float b2 = gp2_b[i_];
        const float g2 = ln2_g[i_], bb2 = ln2_b[i_];
        #pragma unroll
        for (int j = 0; j < 8; ++j) {
            const float v = a2[j] + b2;
            float s = v, s2 = v * v;
            #pragma unroll
            for (int m = 1; m <= 16; m <<= 1) { s += __shfl_xor(s, m, 64); s2 += __shfl_xor(s2, m, 64); }
            const float mean = s * (1.0f / In);
            const float rstd = rsqrtf(s2 * (1.0f / In) - mean * mean + 1e-5f);
            interL[rg2 * 8 + j][i_] = gelu_f((v - mean) * rstd * g2 + bb2);
        }
    }
    __syncthreads();

    // ---------------- Phase 3c: gp3 (32->16) + logits out ------------------
    {
        const int r3 = tid >> 2, e2 = tid & 3;
        float a3[4] = {0.f,0.f,0.f,0.f};
        #pragma unroll 4
        for (int i2 = 0; i2 < In; ++i2) {
            const float v = interL[r3][i2];
            const float4 w3 = *(const float4*)(gp3_w + i2 * En + e2 * 4);
            a3[0] = fmaf(v, w3.x, a3[0]);
            a3[1] = fmaf(v, w3.y, a3[1]);
            a3[2] = fmaf(v, w3.z, a3[2]);
            a3[3] = fmaf(v, w3.w, a3[3]);
        }
        const float4 b3 = *(const float4*)(gp3_b + e2 * 4);
        const float4 lg = make_float4(a3[0] + b3.x, a3[1] + b3.y, a3[2] + b3.z, a3[3] + b3.w);
        *(float4*)&logitsL[r3][e2 * 4] = lg;
        float* outl = out + (size_t)Bn * 4;
        *(float4*)(outl + (size_t)(row0 + r3) * En + e2 * 4) = lg;
    }
    __syncthreads();

    // ---------------- Phase 3d: stable top-2 + softmax ---------------------
    if (tid < Rn) {
        const int r = tid;
        float v[En];
        #pragma unroll
        for (int e = 0; e < En; ++e) v[e] = logitsL[r][e];
        int i0 = 0; float v0 = v[0];
        #pragma unroll
        for (int e = 1; e < En; ++e) if (v[e] > v0) { v0 = v[e]; i0 = e; }
        int i1 = -1; float v1 = -3.4e38f;
        #pragma unroll
        for (int e = 0; e < En; ++e) if (e != i0 && v[e] > v1) { v1 = v[e]; i1 = e; }
        const float e1  = expf(v1 - v0);
        const float inv = 1.0f / (1.0f + e1);
        const size_t g = (size_t)(row0 + r);
        out[g * 2 + 0] = inv;
        out[g * 2 + 1] = e1 * inv;
        float* outi = out + (size_t)Bn * 2;
        outi[g * 2 + 0] = (float)i0;
        outi[g * 2 + 1] = (float)i1;
    }
}

} // namespace

extern "C" void kernel_launch(void* const* d_in, const int* in_sizes, int n_in,
                              void* d_out, int out_size, void* d_ws, size_t ws_size,
                              hipStream_t stream) {
    const float* x     = (const float*)d_in[0];
    const float* ctx   = (const float*)d_in[1];
    const float* en_g  = (const float*)d_in[2];
    const float* en_b  = (const float*)d_in[3];
    const float* cn_g  = (const float*)d_in[4];
    const float* cn_b  = (const float*)d_in[5];
    const float* cp1_w = (const float*)d_in[6];
    const float* cp1_b = (const float*)d_in[7];
    const float* cp2_w = (const float*)d_in[8];
    const float* cp2_b = (const float*)d_in[9];
    const float* cpn_g = (const float*)d_in[10];
    const float* cpn_b = (const float*)d_in[11];
    const float* fn_g  = (const float*)d_in[12];
    const float* fn_b  = (const float*)d_in[13];
    const float* gp1_w = (const float*)d_in[14];
    const float* gp1_b = (const float*)d_in[15];
    const float* ln1_g = (const float*)d_in[16];
    const float* ln1_b = (const float*)d_in[17];
    const float* gp2_w = (const float*)d_in[18];
    const float* gp2_b = (const float*)d_in[19];
    const float* ln2_g = (const float*)d_in[20];
    const float* ln2_b = (const float*)d_in[21];
    const float* gp3_w = (const float*)d_in[22];
    const float* gp3_b = (const float*)d_in[23];

    hipLaunchKernelGGL(cag_fused, dim3(Bn / Rn), dim3(256), 0, stream,
                       x, ctx, en_g, en_b, cn_g, cn_b, cp1_w, cp1_b, cp2_w, cp2_b,
                       cpn_g, cpn_b, fn_g, fn_b, gp1_w, gp1_b, ln1_g, ln1_b,
                       gp2_w, gp2_b, ln2_g, ln2_b, gp3_w, gp3_b, (float*)d_out);
}

// Round 3
// 212.209 us; speedup vs baseline: 3.3918x; 3.3918x over previous
//
#include <hip/hip_runtime.h>
#include <math.h>

namespace {

using s8v = __attribute__((ext_vector_type(8))) short;
using vf4 = __attribute__((ext_vector_type(4))) float;

constexpr int Bn = 65536;
constexpr int Rn = 64;   // rows per block

// ---- workspace layout (bytes) ----
constexpr size_t OFF_A1H  = 0;        // 33*8*64*8 shorts = 270336 B each
constexpr size_t OFF_A1M  = 270336;
constexpr size_t OFF_A1L  = 540672;   // end 811008
constexpr size_t OFF_C1H  = 811008;   // 8*2*64*8 shorts = 16384 B each
constexpr size_t OFF_C1M  = 827392;
constexpr size_t OFF_C1L  = 843776;   // end 860160
constexpr size_t OFF_C2H  = 860160;   // 2*64*8 shorts = 2048 B each
constexpr size_t OFF_C2M  = 862208;
constexpr size_t OFF_C2L  = 864256;   // end 866304
constexpr size_t OFF_G2H  = 866304;   // 4*2*64*8 shorts = 8192 B each
constexpr size_t OFF_G2M  = 874496;
constexpr size_t OFF_G2L  = 882688;   // end 890880
constexpr size_t OFF_VPK  = 890880;   // float[128][4] = 2048 B
constexpr size_t OFF_UPK  = 892928;   // float[32][2] = 256 B
constexpr size_t OFF_CST  = 893184;   // float[8] = 32 B
constexpr size_t OFF_VPART= 893216;   // float[33][128][4] = 67584 B -> end 960800

__device__ __forceinline__ unsigned short bf16_rn(float f) {
    unsigned u = __float_as_uint(f);
    u += 0x7FFFu + ((u >> 16) & 1u);
    return (unsigned short)(u >> 16);
}
__device__ __forceinline__ float bf16_tof(unsigned short h) {
    return __uint_as_float(((unsigned)h) << 16);
}

union S8U { s8v v; unsigned short u[8]; };

__device__ __forceinline__ vf4 MFMA(s8v a, s8v b, vf4 c) {
    return __builtin_amdgcn_mfma_f32_16x16x32_bf16(a, b, c, 0, 0, 0);
}

// 6-product accumulate: exact x=(h+m+l), drops only (m,l),(l,m),(l,l) ~ 2^-26
__device__ __forceinline__ void mfma6(vf4& acc, s8v ah, s8v am, s8v al,
                                      s8v bh, s8v bm, s8v bl) {
    acc = MFMA(ah, bh, acc);
    acc = MFMA(ah, bm, acc);
    acc = MFMA(am, bh, acc);
    acc = MFMA(ah, bl, acc);
    acc = MFMA(al, bh, acc);
    acc = MFMA(am, bm, acc);
}

// exact 3-way split of fp32 into bf16 components (24-bit mantissa = 8+8+8)
__device__ __forceinline__ void split3(float v, unsigned short& h,
                                       unsigned short& m, unsigned short& l) {
    h = bf16_rn(v);
    const float r = v - bf16_tof(h);
    m = bf16_rn(r);
    const float r2 = r - bf16_tof(m);
    l = bf16_rn(r2);   // exact: r2 has <= 8 significant bits
}

__device__ __forceinline__ float gelu_f(float v) {
    return 0.5f * v * (1.0f + erff(v * 0.70710678118654752440f));
}

__device__ __forceinline__ void red16(float& s) {
    s += __shfl_xor(s, 1, 64); s += __shfl_xor(s, 2, 64);
    s += __shfl_xor(s, 4, 64); s += __shfl_xor(s, 8, 64);
}

// ======================= pre-kernel 1: pack big A (gp1) + V partials ======
__global__ void cag_prek1(const float* __restrict__ gp1_w,
                          const float* __restrict__ en_g, const float* __restrict__ en_b,
                          const float* __restrict__ fn_g, const float* __restrict__ fn_b,
                          char* __restrict__ ws)
{
    const int t = threadIdx.x, ch = blockIdx.x;   // ch = k-chunk 0..32
    s8v* A1h = (s8v*)(ws + OFF_A1H);
    s8v* A1m = (s8v*)(ws + OFF_A1M);
    s8v* A1l = (s8v*)(ws + OFF_A1L);
    float* Vpart = (float*)(ws + OFF_VPART);

    for (int s = t; s < 512; s += 256) {           // [nt 8][lane 64]
        const int nt = s >> 6, lane = s & 63;
        const int n = nt * 16 + (lane & 15);
        const int jb = ch * 32 + 8 * (lane >> 4);
        S8U h, m, lo;
        #pragma unroll
        for (int r = 0; r < 8; ++r) {
            const int j = jb + r;
            const float sc = fn_g[j] * (j < 1024 ? en_g[j] : 1.0f);
            const float a = sc * gp1_w[(size_t)j * 128 + n];
            split3(a, h.u[r], m.u[r], lo.u[r]);
        }
        A1h[(ch * 8 + nt) * 64 + lane] = h.v;
        A1m[(ch * 8 + nt) * 64 + lane] = m.v;
        A1l[(ch * 8 + nt) * 64 + lane] = lo.v;
    }
    if (t < 128) {
        float v1 = 0.f, v2 = 0.f, v3 = 0.f, v4 = 0.f;
        for (int jj = 0; jj < 32; ++jj) {
            const int j = ch * 32 + jj;
            const float wv = gp1_w[(size_t)j * 128 + t];
            const float fg = fn_g[j];
            if (j < 1024) { v1 = fmaf(fg * en_g[j], wv, v1); v2 = fmaf(fg * en_b[j], wv, v2); }
            v3 = fmaf(fg, wv, v3);
            v4 = fmaf(fn_b[j], wv, v4);
        }
        float* p = Vpart + ((size_t)ch * 128 + t) * 4;
        p[0] = v1; p[1] = v2; p[2] = v3; p[3] = v4;
    }
}

// ======================= pre-kernel 2: V reduce, consts, small packs ======
__global__ void cag_prek2(const float* __restrict__ en_g, const float* __restrict__ en_b,
                          const float* __restrict__ cn_g, const float* __restrict__ cn_b,
                          const float* __restrict__ cp1_w, const float* __restrict__ cp1_b,
                          const float* __restrict__ cp2_w, const float* __restrict__ gp2_w,
                          const float* __restrict__ gp1_b,
                          char* __restrict__ ws)
{
    const int t = threadIdx.x, b = blockIdx.x;
    if (b == 0) {
        const float* Vpart = (const float*)(ws + OFF_VPART);
        float* Vpk = (float*)(ws + OFF_VPK);
        float* cst = (float*)(ws + OFF_CST);
        if (t < 128) {
            float v1 = 0.f, v2 = 0.f, v3 = 0.f, v4 = 0.f;
            for (int ch = 0; ch < 33; ++ch) {
                const float* p = Vpart + ((size_t)ch * 128 + t) * 4;
                v1 += p[0]; v2 += p[1]; v3 += p[2]; v4 += p[3];
            }
            v4 += gp1_b[t];
            float* q = Vpk + t * 4;
            q[0] = v1; q[1] = v2; q[2] = v3; q[3] = v4;
        }
        __shared__ float red[256];
        float part[5] = {0.f, 0.f, 0.f, 0.f, 0.f};
        for (int i = t; i < 1024; i += 256) {
            const float g = en_g[i], bb = en_b[i];
            part[0] += g; part[1] += bb; part[2] += g * g; part[3] += g * bb; part[4] += bb * bb;
        }
        for (int f = 0; f < 5; ++f) {
            red[t] = part[f]; __syncthreads();
            for (int s = 128; s > 0; s >>= 1) { if (t < s) red[t] += red[t + s]; __syncthreads(); }
            if (t == 0) cst[f] = red[0];
            __syncthreads();
        }
    } else if (b == 1) {
        s8v* C1h = (s8v*)(ws + OFF_C1H);
        s8v* C1m = (s8v*)(ws + OFF_C1M);
        s8v* C1l = (s8v*)(ws + OFF_C1L);
        float* up = (float*)(ws + OFF_UPK);
        for (int s = t; s < 8 * 2 * 64; s += 256) {
            const int ks = s >> 7, nt = (s >> 6) & 1, lane = s & 63;
            const int n = nt * 16 + (lane & 15);
            const int kb = ks * 32 + 8 * (lane >> 4);
            S8U h, m, lo;
            #pragma unroll
            for (int r = 0; r < 8; ++r) {
                const int k = kb + r;
                const float a = cn_g[k] * cp1_w[k * 32 + n];
                split3(a, h.u[r], m.u[r], lo.u[r]);
            }
            C1h[(ks * 2 + nt) * 64 + lane] = h.v;
            C1m[(ks * 2 + nt) * 64 + lane] = m.v;
            C1l[(ks * 2 + nt) * 64 + lane] = lo.v;
        }
        if (t < 32) {
            float u1 = 0.f, u2 = 0.f;
            for (int c = 0; c < 256; ++c) {
                u1 = fmaf(cn_g[c], cp1_w[c * 32 + t], u1);
                u2 = fmaf(cn_b[c], cp1_w[c * 32 + t], u2);
            }
            up[2 * t] = u1; up[2 * t + 1] = u2 + cp1_b[t];
        }
    } else if (b == 2) {
        s8v* C2h = (s8v*)(ws + OFF_C2H);
        s8v* C2m = (s8v*)(ws + OFF_C2M);
        s8v* C2l = (s8v*)(ws + OFF_C2L);
        if (t < 128) {
            const int nt = t >> 6, lane = t & 63;
            const int n = nt * 16 + (lane & 15);
            const int kb = 8 * (lane >> 4);
            S8U h, m, lo;
            #pragma unroll
            for (int r = 0; r < 8; ++r) {
                const float a = cp2_w[(kb + r) * 32 + n];
                split3(a, h.u[r], m.u[r], lo.u[r]);
            }
            C2h[nt * 64 + lane] = h.v;
            C2m[nt * 64 + lane] = m.v;
            C2l[nt * 64 + lane] = lo.v;
        }
    } else {
        s8v* G2h = (s8v*)(ws + OFF_G2H);
        s8v* G2m = (s8v*)(ws + OFF_G2M);
        s8v* G2l = (s8v*)(ws + OFF_G2L);
        for (int s = t; s < 4 * 2 * 64; s += 256) {
            const int ks = s >> 7, nt = (s >> 6) & 1, lane = s & 63;
            const int n = nt * 16 + (lane & 15);
            const int kb = ks * 32 + 8 * (lane >> 4);
            S8U h, m, lo;
            #pragma unroll
            for (int r = 0; r < 8; ++r) {
                const float a = gp2_w[(kb + r) * 32 + n];
                split3(a, h.u[r], m.u[r], lo.u[r]);
            }
            G2h[(ks * 2 + nt) * 64 + lane] = h.v;
            G2m[(ks * 2 + nt) * 64 + lane] = m.v;
            G2l[(ks * 2 + nt) * 64 + lane] = lo.v;
        }
    }
}

// ============================== main kernel ===============================
__global__ __launch_bounds__(256, 2)
void cag_main(const float* __restrict__ x, const float* __restrict__ ctx,
              const float* __restrict__ en_g, const float* __restrict__ en_b,
              const float* __restrict__ cpn_g, const float* __restrict__ cpn_b,
              const float* __restrict__ cp2_b,
              const float* __restrict__ ln1_g, const float* __restrict__ ln1_b,
              const float* __restrict__ gp2_b,
              const float* __restrict__ ln2_g, const float* __restrict__ ln2_b,
              const float* __restrict__ gp3_w, const float* __restrict__ gp3_b,
              const char* __restrict__ ws, float* __restrict__ out)
{
    // big aliased region: pbuf (P0) / fragA (P1 GEMM) / hbuf,ibuf,lbuf (epilogue+)
    __shared__ __attribute__((aligned(16))) char smU[64 * 132 * 4];   // 33792 B
    __shared__ float cfnbuf[64][36];          // 9216 B, persists P0 -> ks31
    __shared__ float s_sc4[64][4];
    __shared__ float part_s[4][64];
    __shared__ float part_s2[4][64];
    __shared__ float s_ln1[64][2];
    __shared__ float s_cfs[64], s_cfs2[64];

    short (*fragA)[3][4][64][8] = (short(*)[3][4][64][8])smU;  // [2][3][4][64][8] = 24576 B
    float (*pbuf)[36]  = (float(*)[36])smU;
    float (*hbuf)[132] = (float(*)[132])smU;
    float (*ibuf)[36]  = (float(*)[36])smU;
    float (*lbuf)[20]  = (float(*)[20])(smU + 16384);

    const int tid = threadIdx.x;
    const int l = tid & 63, w = tid >> 6;
    const int sg = l >> 4, lr = l & 15;
    const int row0 = blockIdx.x * Rn;

    const s8v* A1h = (const s8v*)(ws + OFF_A1H);
    const s8v* A1m = (const s8v*)(ws + OFF_A1M);
    const s8v* A1l = (const s8v*)(ws + OFF_A1L);
    const s8v* C1h = (const s8v*)(ws + OFF_C1H);
    const s8v* C1m = (const s8v*)(ws + OFF_C1M);
    const s8v* C1l = (const s8v*)(ws + OFF_C1L);
    const s8v* C2h = (const s8v*)(ws + OFF_C2H);
    const s8v* C2m = (const s8v*)(ws + OFF_C2M);
    const s8v* C2l = (const s8v*)(ws + OFF_C2L);
    const s8v* G2h = (const s8v*)(ws + OFF_G2H);
    const s8v* G2m = (const s8v*)(ws + OFF_G2M);
    const s8v* G2l = (const s8v*)(ws + OFF_G2L);
    const float* Vpk = (const float*)(ws + OFF_VPK);
    const float* upk = (const float*)(ws + OFF_UPK);
    const float* cst = (const float*)(ws + OFF_CST);

    // ================= P0: context branch (wave-local MFMA) ================
    {
        const int crow = row0 + 16 * w + lr;
        const float* cb = ctx + (size_t)crow * 256 + 8 * sg;
        float cs = 0.f, cs2 = 0.f;
        vf4 ac0 = {0.f, 0.f, 0.f, 0.f}, ac1 = {0.f, 0.f, 0.f, 0.f};
        #pragma unroll
        for (int ks = 0; ks < 8; ++ks) {
            const float4 a0 = *(const float4*)(cb + ks * 32);
            const float4 a1 = *(const float4*)(cb + ks * 32 + 4);
            const float vv[8] = {a0.x, a0.y, a0.z, a0.w, a1.x, a1.y, a1.z, a1.w};
            S8U ah, am, al;
            #pragma unroll
            for (int j = 0; j < 8; ++j) {
                const float v = vv[j];
                cs += v; cs2 = fmaf(v, v, cs2);
                split3(v, ah.u[j], am.u[j], al.u[j]);
            }
            mfma6(ac0, ah.v, am.v, al.v,
                  C1h[(ks * 2 + 0) * 64 + l], C1m[(ks * 2 + 0) * 64 + l], C1l[(ks * 2 + 0) * 64 + l]);
            mfma6(ac1, ah.v, am.v, al.v,
                  C1h[(ks * 2 + 1) * 64 + l], C1m[(ks * 2 + 1) * 64 + l], C1l[(ks * 2 + 1) * 64 + l]);
        }
        cs += __shfl_xor(cs, 16, 64); cs += __shfl_xor(cs, 32, 64);
        cs2 += __shfl_xor(cs2, 16, 64); cs2 += __shfl_xor(cs2, 32, 64);
        const float cm = cs * (1.f / 256.f);
        const float crr = rsqrtf(cs2 * (1.f / 256.f) - cm * cm + 1e-5f);
        float m_r[4], r_r[4];
        #pragma unroll
        for (int rg = 0; rg < 4; ++rg) {
            const int src = 4 * sg + rg;
            m_r[rg] = __shfl(cm, src, 64);
            r_r[rg] = __shfl(crr, src, 64);
        }
        #pragma unroll
        for (int ntl = 0; ntl < 2; ++ntl) {
            const int c = 16 * ntl + lr;
            const float u1 = upk[2 * c], u2 = upk[2 * c + 1];
            #pragma unroll
            for (int rg = 0; rg < 4; ++rg) {
                const float av = (ntl == 0) ? ac0[rg] : ac1[rg];
                const float a1v = r_r[rg] * av - r_r[rg] * m_r[rg] * u1 + u2;
                pbuf[16 * w + 4 * sg + rg][c] = gelu_f(a1v);
            }
        }
        __syncthreads();
        // cp2: restage own rows as A-fragments
        float pv[8];
        const int prow = 16 * w + lr;
        *(float4*)&pv[0] = *(const float4*)&pbuf[prow][8 * sg];
        *(float4*)&pv[4] = *(const float4*)&pbuf[prow][8 * sg + 4];
        S8U ph, pm_, pl;
        #pragma unroll
        for (int j = 0; j < 8; ++j) split3(pv[j], ph.u[j], pm_.u[j], pl.u[j]);
        vf4 a20 = {0.f, 0.f, 0.f, 0.f}, a21 = {0.f, 0.f, 0.f, 0.f};
        mfma6(a20, ph.v, pm_.v, pl.v, C2h[0 * 64 + l], C2m[0 * 64 + l], C2l[0 * 64 + l]);
        mfma6(a21, ph.v, pm_.v, pl.v, C2h[1 * 64 + l], C2m[1 * 64 + l], C2l[1 * 64 + l]);
        const float cb0 = cp2_b[lr], cb1 = cp2_b[16 + lr];
        const float cg0 = cpn_g[lr], cg1 = cpn_g[16 + lr];
        const float cbb0 = cpn_b[lr], cbb1 = cpn_b[16 + lr];
        #pragma unroll
        for (int rg = 0; rg < 4; ++rg) {
            const float v0 = a20[rg] + cb0, v1 = a21[rg] + cb1;
            float s = v0 + v1, s2 = v0 * v0 + v1 * v1;
            red16(s); red16(s2);
            const float pm = s * (1.f / 32.f);
            const float prs = rsqrtf(s2 * (1.f / 32.f) - pm * pm + 1e-5f);
            const float cn0 = (v0 - pm) * prs * cg0 + cbb0;
            const float cn1 = (v1 - pm) * prs * cg1 + cbb1;
            float t = cn0 + cn1, t2 = cn0 * cn0 + cn1 * cn1;
            red16(t); red16(t2);
            const int rr = 16 * w + 4 * sg + rg;
            if (lr == 0) { s_cfs[rr] = t; s_cfs2[rr] = t2; }
            cfnbuf[rr][lr] = cn0; cfnbuf[rr][16 + lr] = cn1;
        }
    }
    __syncthreads();   // pbuf reads done before fragA (aliased) writes

    // ================= P1: main GEMM over K=1056 ===========================
    float Sx = 0.f, Sxx = 0.f, Sxg = 0.f, Sxg2 = 0.f, Sxgb = 0.f, Sxxg2 = 0.f;
    vf4 acc[4][2];
    #pragma unroll
    for (int mt = 0; mt < 4; ++mt) { acc[mt][0] = vf4{0.f,0.f,0.f,0.f}; acc[mt][1] = vf4{0.f,0.f,0.f,0.f}; }

    const float* xb = x + (size_t)(row0 + 16 * w + lr) * 1024 + 8 * sg;
    float xrinv = 0.f;

    auto stage_x = [&](int c, const float4& a0, const float4& a1) {
        const float vv[8] = {a0.x, a0.y, a0.z, a0.w, a1.x, a1.y, a1.z, a1.w};
        const float4 g0 = *(const float4*)(en_g + c * 32 + 8 * sg);
        const float4 g1 = *(const float4*)(en_g + c * 32 + 8 * sg + 4);
        const float4 e0 = *(const float4*)(en_b + c * 32 + 8 * sg);
        const float4 e1 = *(const float4*)(en_b + c * 32 + 8 * sg + 4);
        const float gg[8] = {g0.x, g0.y, g0.z, g0.w, g1.x, g1.y, g1.z, g1.w};
        const float eb[8] = {e0.x, e0.y, e0.z, e0.w, e1.x, e1.y, e1.z, e1.w};
        S8U hh, mm, ll;
        #pragma unroll
        for (int j = 0; j < 8; ++j) {
            const float v = vv[j], g = gg[j], b = eb[j];
            Sx += v; Sxx = fmaf(v, v, Sxx);
            const float tt = v * g;
            Sxg += tt; Sxg2 = fmaf(tt, g, Sxg2); Sxgb = fmaf(tt, b, Sxgb); Sxxg2 = fmaf(tt, tt, Sxxg2);
            split3(v, hh.u[j], mm.u[j], ll.u[j]);
        }
        *(s8v*)&fragA[c & 1][0][w][l][0] = hh.v;
        *(s8v*)&fragA[c & 1][1][w][l][0] = mm.v;
        *(s8v*)&fragA[c & 1][2][w][l][0] = ll.v;
    };

    {
        const float4 t0 = *(const float4*)(xb + 0), t1 = *(const float4*)(xb + 4);
        float4 xA0 = *(const float4*)(xb + 32), xA1 = *(const float4*)(xb + 36);
        stage_x(0, t0, t1);
        __syncthreads();

        const int nt0 = 2 * w, nt1 = 2 * w + 1;
        s8v bn0h = A1h[(0 * 8 + nt0) * 64 + l], bn0m = A1m[(0 * 8 + nt0) * 64 + l], bn0l = A1l[(0 * 8 + nt0) * 64 + l];
        s8v bn1h = A1h[(0 * 8 + nt1) * 64 + l], bn1m = A1m[(0 * 8 + nt1) * 64 + l], bn1l = A1l[(0 * 8 + nt1) * 64 + l];
        float4 xB0, xB1;

        #pragma unroll 1
        for (int ks = 0; ks <= 32; ++ks) {
            const s8v b0h = bn0h, b0m = bn0m, b0l = bn0l;
            const s8v b1h = bn1h, b1m = bn1m, b1l = bn1l;
            if (ks < 32) {
                bn0h = A1h[((ks + 1) * 8 + nt0) * 64 + l]; bn0m = A1m[((ks + 1) * 8 + nt0) * 64 + l]; bn0l = A1l[((ks + 1) * 8 + nt0) * 64 + l];
                bn1h = A1h[((ks + 1) * 8 + nt1) * 64 + l]; bn1m = A1m[((ks + 1) * 8 + nt1) * 64 + l]; bn1l = A1l[((ks + 1) * 8 + nt1) * 64 + l];
            }
            if (ks + 2 <= 31) {
                xB0 = *(const float4*)(xb + (ks + 2) * 32);
                xB1 = *(const float4*)(xb + (ks + 2) * 32 + 4);
            }
            #pragma unroll
            for (int mt = 0; mt < 4; ++mt) {
                const s8v ah = *(const s8v*)&fragA[ks & 1][0][mt][l][0];
                const s8v am = *(const s8v*)&fragA[ks & 1][1][mt][l][0];
                const s8v al = *(const s8v*)&fragA[ks & 1][2][mt][l][0];
                mfma6(acc[mt][0], ah, am, al, b0h, b0m, b0l);
                mfma6(acc[mt][1], ah, am, al, b1h, b1m, b1l);
            }
            if (ks == 31) {
                float sx = Sx, sxx = Sxx, sxg = Sxg, sxg2 = Sxg2, sxgb = Sxgb, sxxg2 = Sxxg2;
                sx += __shfl_xor(sx, 16, 64); sx += __shfl_xor(sx, 32, 64);
                sxx += __shfl_xor(sxx, 16, 64); sxx += __shfl_xor(sxx, 32, 64);
                sxg += __shfl_xor(sxg, 16, 64); sxg += __shfl_xor(sxg, 32, 64);
                sxg2 += __shfl_xor(sxg2, 16, 64); sxg2 += __shfl_xor(sxg2, 32, 64);
                sxgb += __shfl_xor(sxgb, 16, 64); sxgb += __shfl_xor(sxgb, 32, 64);
                sxxg2 += __shfl_xor(sxxg2, 16, 64); sxxg2 += __shfl_xor(sxxg2, 32, 64);
                const float xm = sx * (1.f / 1024.f);
                const float xvar = sxx * (1.f / 1024.f) - xm * xm;
                const float xr = rsqrtf(xvar + 1e-5f);
                xrinv = sqrtf(xvar + 1e-5f);
                const float Gs = cst[0], Bs = cst[1], Sg2c = cst[2], Sgbc = cst[3], Sb2c = cst[4];
                const float Semb = xr * (sxg - xm * Gs) + Bs;
                const float Semb2 = xr * xr * (sxxg2 - 2.f * xm * sxg2 + xm * xm * Sg2c)
                                  + 2.f * xr * (sxgb - xm * Sgbc) + Sb2c;
                const int rr = 16 * w + lr;
                const float fm = (Semb + s_cfs[rr]) * (1.f / 1056.f);
                const float fvar = (Semb2 + s_cfs2[rr]) * (1.f / 1056.f) - fm * fm;
                const float fr = rsqrtf(fvar + 1e-5f);
                if (sg == 0) {
                    s_sc4[rr][0] = fr * xr;
                    s_sc4[rr][1] = -fr * xr * xm;
                    s_sc4[rr][2] = fr;
                    s_sc4[rr][3] = -fr * fm;
                }
            }
            if (ks < 31) {
                stage_x(ks + 1, xA0, xA1);
                xA0 = xB0; xA1 = xB1;
            } else if (ks == 31) {
                const int rr = 16 * w + lr;
                float vv[8];
                *(float4*)&vv[0] = *(const float4*)&cfnbuf[rr][8 * sg];
                *(float4*)&vv[4] = *(const float4*)&cfnbuf[rr][8 * sg + 4];
                S8U hh, mm, ll;
                #pragma unroll
                for (int j = 0; j < 8; ++j) split3(vv[j] * xrinv, hh.u[j], mm.u[j], ll.u[j]);
                *(s8v*)&fragA[0][0][w][l][0] = hh.v;
                *(s8v*)&fragA[0][1][w][l][0] = mm.v;
                *(s8v*)&fragA[0][2][w][l][0] = ll.v;
            }
            __syncthreads();
        }
    }

    // ================= epilogue: scalars + LN1 + gelu -> hbuf ==============
    {
        float4 Vc[2];
        #pragma unroll
        for (int ntl = 0; ntl < 2; ++ntl)
            Vc[ntl] = *(const float4*)&Vpk[(16 * (2 * w + ntl) + lr) * 4];
        #pragma unroll
        for (int mt = 0; mt < 4; ++mt) {
            #pragma unroll
            for (int rg = 0; rg < 4; ++rg) {
                const float4 sc = *(const float4*)&s_sc4[16 * mt + 4 * sg + rg][0];
                #pragma unroll
                for (int ntl = 0; ntl < 2; ++ntl) {
                    acc[mt][ntl][rg] = sc.x * acc[mt][ntl][rg] + sc.y * Vc[ntl].x
                                     + sc.z * Vc[ntl].y + sc.w * Vc[ntl].z + Vc[ntl].w;
                }
            }
        }
        #pragma unroll
        for (int mt = 0; mt < 4; ++mt) {
            #pragma unroll
            for (int rg = 0; rg < 4; ++rg) {
                const float v0 = acc[mt][0][rg], v1 = acc[mt][1][rg];
                float s = v0 + v1, s2 = v0 * v0 + v1 * v1;
                red16(s); red16(s2);
                if (lr == 0) {
                    const int rr = 16 * mt + 4 * sg + rg;
                    part_s[w][rr] = s; part_s2[w][rr] = s2;
                }
            }
        }
        __syncthreads();
        if (tid < 64) {
            const float s = part_s[0][tid] + part_s[1][tid] + part_s[2][tid] + part_s[3][tid];
            const float s2 = part_s2[0][tid] + part_s2[1][tid] + part_s2[2][tid] + part_s2[3][tid];
            const float mn = s * (1.f / 128.f);
            s_ln1[tid][0] = mn;
            s_ln1[tid][1] = rsqrtf(s2 * (1.f / 128.f) - mn * mn + 1e-5f);
        }
        __syncthreads();
        float g1c[2], b1c[2];
        #pragma unroll
        for (int ntl = 0; ntl < 2; ++ntl) {
            const int c = 16 * (2 * w + ntl) + lr;
            g1c[ntl] = ln1_g[c]; b1c[ntl] = ln1_b[c];
        }
        #pragma unroll
        for (int mt = 0; mt < 4; ++mt) {
            #pragma unroll
            for (int rg = 0; rg < 4; ++rg) {
                const int rr = 16 * mt + 4 * sg + rg;
                const float mn = s_ln1[rr][0], rs = s_ln1[rr][1];
                #pragma unroll
                for (int ntl = 0; ntl < 2; ++ntl) {
                    const float hp = gelu_f((acc[mt][ntl][rg] - mn) * rs * g1c[ntl] + b1c[ntl]);
                    hbuf[rr][16 * (2 * w + ntl) + lr] = hp;
                }
            }
        }
        __syncthreads();
    }

    // ================= P2: gp2 (128->32) + LN2 + gelu ======================
    float iv[2][4];
    {
        vf4 aG0 = {0.f, 0.f, 0.f, 0.f}, aG1 = {0.f, 0.f, 0.f, 0.f};
        const int hrow = 16 * w + lr;
        #pragma unroll
        for (int ks = 0; ks < 4; ++ks) {
            float pv[8];
            *(float4*)&pv[0] = *(const float4*)&hbuf[hrow][ks * 32 + 8 * sg];
            *(float4*)&pv[4] = *(const float4*)&hbuf[hrow][ks * 32 + 8 * sg + 4];
            S8U ah, am, al;
            #pragma unroll
            for (int j = 0; j < 8; ++j) split3(pv[j], ah.u[j], am.u[j], al.u[j]);
            mfma6(aG0, ah.v, am.v, al.v,
                  G2h[(ks * 2 + 0) * 64 + l], G2m[(ks * 2 + 0) * 64 + l], G2l[(ks * 2 + 0) * 64 + l]);
            mfma6(aG1, ah.v, am.v, al.v,
                  G2h[(ks * 2 + 1) * 64 + l], G2m[(ks * 2 + 1) * 64 + l], G2l[(ks * 2 + 1) * 64 + l]);
        }
        const float gb0 = gp2_b[lr], gb1 = gp2_b[16 + lr];
        const float lg0 = ln2_g[lr], lg1 = ln2_g[16 + lr];
        const float lb0 = ln2_b[lr], lb1 = ln2_b[16 + lr];
        #pragma unroll
        for (int rg = 0; rg < 4; ++rg) {
            const float v0 = aG0[rg] + gb0, v1 = aG1[rg] + gb1;
            float s = v0 + v1, s2 = v0 * v0 + v1 * v1;
            red16(s); red16(s2);
            const float mn = s * (1.f / 32.f);
            const float rs = rsqrtf(s2 * (1.f / 32.f) - mn * mn + 1e-5f);
            iv[0][rg] = gelu_f((v0 - mn) * rs * lg0 + lb0);
            iv[1][rg] = gelu_f((v1 - mn) * rs * lg1 + lb1);
        }
    }
    __syncthreads();     // all hbuf reads done before ibuf overwrite
    #pragma unroll
    for (int rg = 0; rg < 4; ++rg) {
        const int rr = 16 * w + 4 * sg + rg;
        ibuf[rr][lr] = iv[0][rg];
        ibuf[rr][16 + lr] = iv[1][rg];
    }
    __syncthreads();

    // ================= P3: gp3 (32->16) + logits + top-2 ===================
    {
        const int r = tid >> 2, e4 = (tid & 3) * 4;
        float a0 = 0.f, a1 = 0.f, a2 = 0.f, a3 = 0.f;
        #pragma unroll 4
        for (int q = 0; q < 32; ++q) {
            const float v = ibuf[r][q];
            const float4 w3 = *(const float4*)(gp3_w + q * 16 + e4);
            a0 = fmaf(v, w3.x, a0); a1 = fmaf(v, w3.y, a1);
            a2 = fmaf(v, w3.z, a2); a3 = fmaf(v, w3.w, a3);
        }
        const float4 b3 = *(const float4*)(gp3_b + e4);
        const float4 lg = make_float4(a0 + b3.x, a1 + b3.y, a2 + b3.z, a3 + b3.w);
        float* outl = out + (size_t)Bn * 4;
        *(float4*)(outl + (size_t)(row0 + r) * 16 + e4) = lg;
        *(float4*)&lbuf[r][e4] = lg;
    }
    __syncthreads();
    if (tid < 64) {
        float v[16];
        #pragma unroll
        for (int e = 0; e < 4; ++e) *(float4*)&v[e * 4] = *(const float4*)&lbuf[tid][e * 4];
        int i0 = 0; float v0 = v[0];
        #pragma unroll
        for (int e = 1; e < 16; ++e) if (v[e] > v0) { v0 = v[e]; i0 = e; }
        int i1 = -1; float v1 = -3.4e38f;
        #pragma unroll
        for (int e = 0; e < 16; ++e) if (e != i0 && v[e] > v1) { v1 = v[e]; i1 = e; }
        const float e1 = expf(v1 - v0);
        const float inv = 1.0f / (1.0f + e1);
        const size_t g = (size_t)(row0 + tid);
        out[g * 2 + 0] = inv;
        out[g * 2 + 1] = e1 * inv;
        float* outi = out + (size_t)Bn * 2;
        outi[g * 2 + 0] = (float)i0;
        outi[g * 2 + 1] = (float)i1;
    }
}

} // namespace

extern "C" void kernel_launch(void* const* d_in, const int* in_sizes, int n_in,
                              void* d_out, int out_size, void* d_ws, size_t ws_size,
                              hipStream_t stream) {
    const float* x     = (const float*)d_in[0];
    const float* ctx   = (const float*)d_in[1];
    const float* en_g  = (const float*)d_in[2];
    const float* en_b  = (const float*)d_in[3];
    const float* cn_g  = (const float*)d_in[4];
    const float* cn_b  = (const float*)d_in[5];
    const float* cp1_w = (const float*)d_in[6];
    const float* cp1_b = (const float*)d_in[7];
    const float* cp2_w = (const float*)d_in[8];
    const float* cp2_b = (const float*)d_in[9];
    const float* cpn_g = (const float*)d_in[10];
    const float* cpn_b = (const float*)d_in[11];
    const float* fn_g  = (const float*)d_in[12];
    const float* fn_b  = (const float*)d_in[13];
    const float* gp1_w = (const float*)d_in[14];
    const float* gp1_b = (const float*)d_in[15];
    const float* ln1_g = (const float*)d_in[16];
    const float* ln1_b = (const float*)d_in[17];
    const float* gp2_w = (const float*)d_in[18];
    const float* gp2_b = (const float*)d_in[19];
    const float* ln2_g = (const float*)d_in[20];
    const float* ln2_b = (const float*)d_in[21];
    const float* gp3_w = (const float*)d_in[22];
    const float* gp3_b = (const float*)d_in[23];

    char* ws = (char*)d_ws;
    hipLaunchKernelGGL(cag_prek1, dim3(33), dim3(256), 0, stream,
                       gp1_w, en_g, en_b, fn_g, fn_b, ws);
    hipLaunchKernelGGL(cag_prek2, dim3(4), dim3(256), 0, stream,
                       en_g, en_b, cn_g, cn_b, cp1_w, cp1_b, cp2_w, gp2_w, gp1_b, ws);
    hipLaunchKernelGGL(cag_main, dim3(Bn / Rn), dim3(256), 0, stream,
                       x, ctx, en_g, en_b, cpn_g, cpn_b, cp2_b,
                       ln1_g, ln1_b, gp2_b, ln2_g, ln2_b, gp3_w, gp3_b,
                       ws, (float*)d_out);
}